// Round 11
// baseline (922.780 us; speedup 1.0000x reference)
//
#include <hip/hip_runtime.h>

typedef _Float16 half8 __attribute__((ext_vector_type(8)));
typedef float f32x4 __attribute__((ext_vector_type(4)));

#define B_ 4
#define C_ 64
#define N_ 8192
#define K_ 20
#define LCELL 8                   // per-(split,class) sorted list depth
#define NSPLIT 2
#define NCAND (16 * LCELL * NSPLIT)  // 256 candidates per query into refine
#define CNT_TOTAL (B_ * N_ * K_)  // 655360
#define BN_EPSF 1e-5f

__device__ __forceinline__ f32x4 max4(f32x4 a, f32x4 b) {
  f32x4 r;
  r.x = fmaxf(a.x, b.x); r.y = fmaxf(a.y, b.y);
  r.z = fmaxf(a.z, b.z); r.w = fmaxf(a.w, b.w);
  return r;
}
__device__ __forceinline__ f32x4 min4(f32x4 a, f32x4 b) {
  f32x4 r;
  r.x = fminf(a.x, b.x); r.y = fminf(a.y, b.y);
  r.z = fminf(a.z, b.z); r.w = fminf(a.w, b.w);
  return r;
}

// ---- Kernel 1: transpose x -> xt (f32 + f16), per-point sq (f32+f64),
// y1 = xt*W1^T, y2 = xt*W2^T - y1. W row o==lane held in 128 VGPRs.
__global__ __launch_bounds__(256) void prep_kernel(
    const float* __restrict__ x, const float* __restrict__ W,
    float* __restrict__ xt, _Float16* __restrict__ xt16,
    float* __restrict__ sq, double* __restrict__ sqd,
    float* __restrict__ y1, float* __restrict__ y2) {
  __shared__ float xs[64 * 68];  // [n][c], stride 68 (16B-aligned rows)
  int b = blockIdx.x >> 7;
  int n0 = (blockIdx.x & 127) * 64;
  int t = threadIdx.x;
  int lane = t & 63;
  int wv = t >> 6;
#pragma unroll
  for (int i = 0; i < 16; ++i) {
    int lin = i * 256 + t;
    int c = lin >> 6, j = lin & 63;
    xs[j * 68 + c] = x[((b * 64 + c) * N_) + n0 + j];
  }
  // W row o = lane into registers (L1/L2-hot, 32 KB total)
  float4 w1[16], w2[16];
  const float4* wr = (const float4*)(W + lane * 128);
#pragma unroll
  for (int u = 0; u < 16; ++u) {
    w1[u] = wr[u];
    w2[u] = wr[16 + u];
  }
  __syncthreads();
#pragma unroll 2
  for (int i = 0; i < 16; ++i) {
    int nl = i * 4 + wv;
    const float4* xr = (const float4*)&xs[nl * 68];
    float d1 = 0.f, d2 = 0.f;
#pragma unroll
    for (int u = 0; u < 16; ++u) {
      float4 xv = xr[u];
      d1 = fmaf(xv.x, w1[u].x, d1); d1 = fmaf(xv.y, w1[u].y, d1);
      d1 = fmaf(xv.z, w1[u].z, d1); d1 = fmaf(xv.w, w1[u].w, d1);
      d2 = fmaf(xv.x, w2[u].x, d2); d2 = fmaf(xv.y, w2[u].y, d2);
      d2 = fmaf(xv.z, w2[u].z, d2); d2 = fmaf(xv.w, w2[u].w, d2);
    }
    int n = n0 + nl;
    y1[((b * N_) + n) * 64 + lane] = d1;
    y2[((b * N_) + n) * 64 + lane] = d2 - d1;
  }
#pragma unroll
  for (int i = 0; i < 16; ++i) {
    int lin = i * 256 + t;
    int c = lin & 63, nl = lin >> 6;
    float v = xs[nl * 68 + c];
    size_t o = ((size_t)(b * N_) + n0 + nl) * 64 + c;
    xt[o] = v;
    xt16[o] = (_Float16)v;
  }
  if (t < 64) {
    float s = 0.f;
    double sd = 0.0;
#pragma unroll
    for (int c = 0; c < 64; ++c) {
      float v = xs[t * 68 + c];
      s = fmaf(v, v, s);
      sd = fma((double)v, (double)v, sd);
    }
    sq[b * N_ + n0 + t] = s;
    sqd[b * N_ + n0 + t] = sd;
  }
}

// ---- Kernel 2: MFMA distance scan over one of 2 candidate splits (4096
// cands). Branchless clamp top-8 per (query,class). Packed key:
// (float_bits(sqc+512-2dot) & ~255) | tile_id(8b). Incremental pointers,
// 2x unrolled (no B-copy movs). __launch_bounds__(256,4): 128-VGPR budget
// so dl[] stays in arch VGPRs (no accvgpr round-trips).
__global__ __launch_bounds__(256, 4) void knn_mfma_kernel(
    const _Float16* __restrict__ xt16, const float* __restrict__ sq,
    int* __restrict__ pidx) {
  int t = threadIdx.x;
  int wave = t >> 6;
  int lane = t & 63;
  int col = lane & 15;
  int quad = lane >> 4;
  int blk = blockIdx.x;
  int split = blk & 1;
  int qt = (blk >> 1) & 127;
  int b = blk >> 8;
  int q0 = qt * 64 + wave * 16;
  size_t bbase = (size_t)b * N_;

  // A fragments: A[m=col][k=quad*8+j] -> query row q0+col
  const _Float16* arow = xt16 + (bbase + q0 + col) * 64;
  half8 A0 = *(const half8*)(arow + quad * 8);
  half8 A1 = *(const half8*)(arow + 32 + quad * 8);

  int dl[4][LCELL];
#pragma unroll
  for (int r = 0; r < 4; ++r)
#pragma unroll
    for (int j = 0; j < LCELL; ++j) dl[r][j] = 0x7fffffff;

  int c0 = split * (N_ / NSPLIT);
  const _Float16* bp = xt16 + (bbase + c0 + col) * 64 + quad * 8;
  const float* sp = sq + bbase + c0 + col;
  half8 B0 = *(const half8*)bp;
  half8 B1 = *(const half8*)(bp + 32);
  float sc = *sp;

  for (int ct = 0; ct < N_ / NSPLIT / 16; ct += 2) {
    // prefetch tile ct+1
    half8 C0 = *(const half8*)(bp + 1024);
    half8 C1 = *(const half8*)(bp + 1024 + 32);
    float sc1 = sp[16];

    f32x4 acc = {0.f, 0.f, 0.f, 0.f};
    acc = __builtin_amdgcn_mfma_f32_16x16x32_f16(A0, B0, acc, 0, 0, 0);
    acc = __builtin_amdgcn_mfma_f32_16x16x32_f16(A1, B1, acc, 0, 0, 0);
    float k512 = sc + 512.0f;
#pragma unroll
    for (int r = 0; r < 4; ++r) {
      float key = fmaf(acc[r], -2.0f, k512);  // positive by construction
      int v = (__float_as_int(key) & ~255) | ct;
#pragma unroll
      for (int j = LCELL - 1; j >= 1; --j)
        dl[r][j] = min(max(v, dl[r][j - 1]), dl[r][j]);
      dl[r][0] = min(dl[r][0], v);
    }

    // prefetch tile ct+2
    B0 = *(const half8*)(bp + 2048);
    B1 = *(const half8*)(bp + 2048 + 32);
    sc = sp[32];

    f32x4 acc2 = {0.f, 0.f, 0.f, 0.f};
    acc2 = __builtin_amdgcn_mfma_f32_16x16x32_f16(A0, C0, acc2, 0, 0, 0);
    acc2 = __builtin_amdgcn_mfma_f32_16x16x32_f16(A1, C1, acc2, 0, 0, 0);
    float k512b = sc1 + 512.0f;
    int ctb = ct + 1;
#pragma unroll
    for (int r = 0; r < 4; ++r) {
      float key = fmaf(acc2[r], -2.0f, k512b);
      int v = (__float_as_int(key) & ~255) | ctb;
#pragma unroll
      for (int j = LCELL - 1; j >= 1; --j)
        dl[r][j] = min(max(v, dl[r][j - 1]), dl[r][j]);
      dl[r][0] = min(dl[r][0], v);
    }
    bp += 2048;
    sp += 32;
  }
#pragma unroll
  for (int r = 0; r < 4; ++r) {
    int q = q0 + quad * 4 + r;
    int* o = pidx + (bbase + q) * NCAND + split * (16 * LCELL) + col * LCELL;
#pragma unroll
    for (int j = 0; j < LCELL; ++j)
      o[j] = ((dl[r][j] & 255) << 4) + col + c0;  // global candidate index
  }
}

// ---- Kernel 3: refinement v5 — one WAVE per point, two-phase.
// Phase 1: lane owns 4 candidates + full fp32 query row in VGPRs; fp32
// cancellation key, packed into (double)key with 13-bit index in the 29
// zero mantissa bits. NO cross-lane work. Sort-4 per lane.
// Phase 2: 24 pop-min steps (6-shfl f64 butterfly); each popped candidate's
// key recomputed EXACTLY in cooperative fp64 (identical math to the passing
// r2-r8 rounds: chunk dot + butterfly + sqd-2dot+1024, index in mantissa).
// fp32 error ~1e-5 << candidate gaps -> true top-20 within fp32-top-24.
// Final: 20 pop-min over the 24 exact keys.
__global__ __launch_bounds__(256, 4) void refine_kernel(
    const float* __restrict__ xt, const float* __restrict__ sq,
    const double* __restrict__ sqd, const int* __restrict__ pidx,
    int* __restrict__ idxf) {
  int tid = threadIdx.x;
  int wave = tid >> 6, lane = tid & 63;
  int u = lane & 15;
  int p = blockIdx.x * 4 + wave;  // global point id
  int b = p >> 13;
  size_t bbase = (size_t)b * N_;
  int plocal = p & (N_ - 1);

  // full fp32 query row (64 VGPRs, constant-indexed)
  float q[64];
  const f32x4* qrow = (const f32x4*)(xt + (size_t)p * 64);
#pragma unroll
  for (int t2 = 0; t2 < 16; ++t2) {
    f32x4 v = qrow[t2];
    q[t2 * 4 + 0] = v.x; q[t2 * 4 + 1] = v.y;
    q[t2 * 4 + 2] = v.z; q[t2 * 4 + 3] = v.w;
  }
  // phase 1: 4 whole candidates per lane, fp32 dots, no shuffles
  const int* pi = pidx + (size_t)p * NCAND + lane * 4;
  int4 cc = *(const int4*)pi;
  int cs[4] = {cc.x, cc.y, cc.z, cc.w};
  double dl[4];
#pragma unroll
  for (int j = 0; j < 4; ++j) {
    int ci = cs[j];
    const f32x4* cr = (const f32x4*)(xt + (bbase + ci) * 64);
    float a0 = 0.f, a1 = 0.f, a2 = 0.f, a3 = 0.f;
#pragma unroll
    for (int t2 = 0; t2 < 16; ++t2) {
      f32x4 v = cr[t2];
      a0 = fmaf(v.x, q[t2 * 4 + 0], a0);
      a1 = fmaf(v.y, q[t2 * 4 + 1], a1);
      a2 = fmaf(v.z, q[t2 * 4 + 2], a2);
      a3 = fmaf(v.w, q[t2 * 4 + 3], a3);
    }
    float dot = (a0 + a1) + (a2 + a3);
    float key = fmaf(dot, -2.0f, sq[bbase + ci]) + 512.0f;  // > 0
    long long bits =
        (__double_as_longlong((double)key) & ~0x1FFFLL) | (long long)ci;
    double v = __longlong_as_double(bits);
    if (ci == plocal) v = 1e300;  // self-exclusion
    dl[j] = v;
  }
  {  // sort 4 ascending
    double lo, hi;
    lo = fmin(dl[0], dl[1]); hi = fmax(dl[0], dl[1]); dl[0] = lo; dl[1] = hi;
    lo = fmin(dl[2], dl[3]); hi = fmax(dl[2], dl[3]); dl[2] = lo; dl[3] = hi;
    lo = fmin(dl[0], dl[2]); hi = fmax(dl[0], dl[2]); dl[0] = lo; dl[2] = hi;
    lo = fmin(dl[1], dl[3]); hi = fmax(dl[1], dl[3]); dl[1] = lo; dl[3] = hi;
    lo = fmin(dl[1], dl[2]); hi = fmax(dl[1], dl[2]); dl[1] = lo; dl[2] = hi;
  }
  double vh = dl[0], h1 = dl[1], h2 = dl[2], h3 = dl[3];

  // phase-2 query chunk in fp64 (dims u*4..u*4+3)
  f32x4 qc = *(const f32x4*)(xt + (size_t)p * 64 + u * 4);
  double q0 = (double)qc.x, q1 = (double)qc.y;
  double q2 = (double)qc.z, q3 = (double)qc.w;

  double kv = 1e300;  // exact-key slot (lanes 0..23)
#pragma unroll
  for (int s = 0; s < 24; ++s) {
    double m = vh;
    m = fmin(m, __shfl_xor(m, 1, 64));
    m = fmin(m, __shfl_xor(m, 2, 64));
    m = fmin(m, __shfl_xor(m, 4, 64));
    m = fmin(m, __shfl_xor(m, 8, 64));
    m = fmin(m, __shfl_xor(m, 16, 64));
    m = fmin(m, __shfl_xor(m, 32, 64));
    int ci = (int)(__double_as_longlong(m) & 0x1FFFLL);
    // exact fp64 key (cooperative, identical math to passing rounds)
    f32x4 cv = *(const f32x4*)(xt + (bbase + ci) * 64 + u * 4);
    double a = q0 * (double)cv.x;
    a = fma(q1, (double)cv.y, a);
    a = fma(q2, (double)cv.z, a);
    a = fma(q3, (double)cv.w, a);
    a += __shfl_xor(a, 1, 64);
    a += __shfl_xor(a, 2, 64);
    a += __shfl_xor(a, 4, 64);
    a += __shfl_xor(a, 8, 64);
    double kd = fma(a, -2.0, sqd[bbase + ci]) + 1024.0;
    long long kb = (__double_as_longlong(kd) & ~0x1FFFLL) | (long long)ci;
    double vv = __longlong_as_double(kb);
    kv = (lane == s) ? vv : kv;
    bool adv = (vh == m);  // unique keys: exactly one owner advances
    vh = adv ? h1 : vh;
    h1 = adv ? h2 : h1;
    h2 = adv ? h3 : h2;
    h3 = adv ? 1e300 : h3;
  }
  // final: 20 smallest of the 24 exact keys (ascending, index tie-break)
  int* o = idxf + (size_t)p * K_;
#pragma unroll
  for (int s = 0; s < K_; ++s) {
    double m = kv;
    m = fmin(m, __shfl_xor(m, 1, 64));
    m = fmin(m, __shfl_xor(m, 2, 64));
    m = fmin(m, __shfl_xor(m, 4, 64));
    m = fmin(m, __shfl_xor(m, 8, 64));
    m = fmin(m, __shfl_xor(m, 16, 64));
    m = fmin(m, __shfl_xor(m, 32, 64));
    if (lane == 0) o[s] = (int)(__double_as_longlong(m) & 0x1FFFLL);
    kv = (kv == m) ? 1e300 : kv;
  }
}

// ---- Kernel 4: one WAVE per point. Lane (u=lane&15, jb=lane>>4); 5 rounds:
// lane loads 16B chunk u of neighbor jb+4r -> each 16-lane group reads a full
// 256B y1 row per instruction (no partial lines). max/min/sum/sumsq of the
// gathered y1 reduced across jb via shfl_xor(16,32); y2 applied once:
// max(h)=max(g)+y2, sum(h)=sum(g)+K*y2, sumsq(h)=sum(g^2)+2*y2*sum(g)+K*y2^2.
// 4 points per wave sequentially; BN sums -> LDS atomics -> 128 global/block.
__global__ __launch_bounds__(256) void stats_kernel(
    const float* __restrict__ y1, const float* __restrict__ y2,
    const int* __restrict__ idxf, float* __restrict__ maxh,
    float* __restrict__ minh, float* __restrict__ gsum,
    float* __restrict__ gsq) {
  __shared__ float lsum[64], lsq[64];
  int tid = threadIdx.x;
  if (tid < 64) { lsum[tid] = 0.f; lsq[tid] = 0.f; }
  __syncthreads();
  int wv = tid >> 6, lane = tid & 63;
  int u = lane & 15, jb = lane >> 4;
  int p0 = blockIdx.x * 16 + wv * 4;  // 16 contiguous points per block
  size_t nb = (size_t)((p0 >> 13) * N_);
  f32x4 css = {0.f, 0.f, 0.f, 0.f}, cqq = {0.f, 0.f, 0.f, 0.f};
#pragma unroll
  for (int it = 0; it < 4; ++it) {
    int p = p0 + it;
    int idxval = (lane < K_) ? idxf[(size_t)p * K_ + lane] : 0;
    int n0 = __shfl(idxval, jb, 64);
    int n1 = __shfl(idxval, jb + 4, 64);
    int n2 = __shfl(idxval, jb + 8, 64);
    int n3 = __shfl(idxval, jb + 12, 64);
    int n4 = __shfl(idxval, jb + 16, 64);
    f32x4 g0 = ((const f32x4*)(y1 + (nb + n0) * 64))[u];
    f32x4 g1 = ((const f32x4*)(y1 + (nb + n1) * 64))[u];
    f32x4 g2 = ((const f32x4*)(y1 + (nb + n2) * 64))[u];
    f32x4 g3 = ((const f32x4*)(y1 + (nb + n3) * 64))[u];
    f32x4 g4 = ((const f32x4*)(y1 + (nb + n4) * 64))[u];
    f32x4 mx = g0, mn = g0, sm = g0, s2 = g0 * g0;
    mx = max4(mx, g1); mn = min4(mn, g1); sm += g1; s2 += g1 * g1;
    mx = max4(mx, g2); mn = min4(mn, g2); sm += g2; s2 += g2 * g2;
    mx = max4(mx, g3); mn = min4(mn, g3); sm += g3; s2 += g3 * g3;
    mx = max4(mx, g4); mn = min4(mn, g4); sm += g4; s2 += g4 * g4;
#pragma unroll
    for (int c = 0; c < 4; ++c) {
      mx[c] = fmaxf(mx[c], __shfl_xor(mx[c], 16, 64));
      mx[c] = fmaxf(mx[c], __shfl_xor(mx[c], 32, 64));
      mn[c] = fminf(mn[c], __shfl_xor(mn[c], 16, 64));
      mn[c] = fminf(mn[c], __shfl_xor(mn[c], 32, 64));
      sm[c] += __shfl_xor(sm[c], 16, 64);
      sm[c] += __shfl_xor(sm[c], 32, 64);
      s2[c] += __shfl_xor(s2[c], 16, 64);
      s2[c] += __shfl_xor(s2[c], 32, 64);
    }
    if (jb == 0) {  // lanes 0..15: full 256B contiguous stores
      f32x4 y2c = ((const f32x4*)(y2 + (size_t)p * 64))[u];
      ((f32x4*)(maxh + (size_t)p * 64))[u] = mx + y2c;
      ((f32x4*)(minh + (size_t)p * 64))[u] = mn + y2c;
      css += sm + 20.0f * y2c;
      cqq += s2 + 2.0f * y2c * sm + 20.0f * y2c * y2c;
    }
  }
  if (jb == 0) {
#pragma unroll
    for (int c = 0; c < 4; ++c) {
      atomicAdd(&lsum[u * 4 + c], css[c]);
      atomicAdd(&lsq[u * 4 + c], cqq[c]);
    }
  }
  __syncthreads();
  if (tid < 64) {
    atomicAdd(&gsum[tid], lsum[tid]);
    atomicAdd(&gsq[tid], lsq[tid]);
  }
}

// ---- Kernel 5: affine + relu + max-over-k selection, transposed store ----
__global__ __launch_bounds__(256) void final_kernel(
    const float* __restrict__ maxh, const float* __restrict__ minh,
    const float* __restrict__ gsum, const float* __restrict__ gsq,
    const float* __restrict__ gamma, const float* __restrict__ beta,
    float* __restrict__ out) {
  __shared__ float sc[64], cc_[64];
  __shared__ float tile[64 * 65];
  int b = blockIdx.x >> 7;
  int n0 = (blockIdx.x & 127) * 64;
  int t = threadIdx.x;
  if (t < 64) {
    float mean = gsum[t] * (1.0f / CNT_TOTAL);
    float var = gsq[t] * (1.0f / CNT_TOTAL) - mean * mean;
    float s = gamma[t] * rsqrtf(var + BN_EPSF);
    sc[t] = s;
    cc_[t] = beta[t] - mean * s;
  }
  __syncthreads();
#pragma unroll
  for (int i = 0; i < 16; ++i) {
    int lin = i * 256 + t;
    int o = lin & 63, nl = lin >> 6;
    size_t off = ((size_t)(b * N_) + n0 + nl) * 64 + o;
    float s = sc[o];
    float v = (s >= 0.f) ? maxh[off] : minh[off];
    float val = fmaxf(fmaf(v, s, cc_[o]), 0.f);
    tile[o * 65 + nl] = val;
  }
  __syncthreads();
#pragma unroll
  for (int i = 0; i < 16; ++i) {
    int lin = i * 256 + t;
    int nl = lin & 63, o = lin >> 6;
    out[((size_t)(b * 64) + o) * N_ + n0 + nl] = tile[o * 65 + nl];
  }
}

extern "C" void kernel_launch(void* const* d_in, const int* in_sizes, int n_in,
                              void* d_out, int out_size, void* d_ws,
                              size_t ws_size, hipStream_t stream) {
  const float* x = (const float*)d_in[0];
  const float* W = (const float*)d_in[1];
  const float* gamma = (const float*)d_in[2];
  const float* beta = (const float*)d_in[3];
  float* out = (float*)d_out;

  char* ws = (char*)d_ws;
  size_t off = 0;
  auto alloc = [&](size_t bytes) {
    char* p = ws + off;
    off += (bytes + 255) & ~(size_t)255;
    return p;
  };
  float* xt = (float*)alloc((size_t)B_ * N_ * 64 * 4);
  _Float16* xt16 = (_Float16*)alloc((size_t)B_ * N_ * 64 * 2);
  float* y1 = (float*)alloc((size_t)B_ * N_ * 64 * 4);
  float* y2 = (float*)alloc((size_t)B_ * N_ * 64 * 4);
  float* sq = (float*)alloc((size_t)B_ * N_ * 4);
  double* sqd = (double*)alloc((size_t)B_ * N_ * 8);
  int* pidx = (int*)alloc((size_t)B_ * N_ * NCAND * 4);  // 33.5 MB
  float* maxh = (float*)alloc((size_t)B_ * N_ * 64 * 4);
  int* idxf = (int*)alloc((size_t)B_ * N_ * K_ * 4);
  float* gsum = (float*)alloc(256);
  float* gsq = (float*)alloc(256);
  // minh aliases pidx (pidx fully consumed by refine before stats runs)
  float* minh = (float*)pidx;

  hipMemsetAsync(gsum, 0, 256, stream);
  hipMemsetAsync(gsq, 0, 256, stream);

  prep_kernel<<<B_ * (N_ / 64), 256, 0, stream>>>(x, W, xt, xt16, sq, sqd,
                                                  y1, y2);
  knn_mfma_kernel<<<B_ * (N_ / 64) * NSPLIT, 256, 0, stream>>>(xt16, sq, pidx);
  refine_kernel<<<(B_ * N_) / 4, 256, 0, stream>>>(xt, sq, sqd, pidx, idxf);
  stats_kernel<<<(B_ * N_) / 16, 256, 0, stream>>>(y1, y2, idxf, maxh, minh,
                                                   gsum, gsq);
  final_kernel<<<B_ * (N_ / 64), 256, 0, stream>>>(maxh, minh, gsum, gsq,
                                                   gamma, beta, out);
}

// Round 12
// 734.934 us; speedup vs baseline: 1.2556x; 1.2556x over previous
//
#include <hip/hip_runtime.h>

typedef _Float16 half8 __attribute__((ext_vector_type(8)));
typedef float f32x4 __attribute__((ext_vector_type(4)));

#define B_ 4
#define C_ 64
#define N_ 8192
#define K_ 20
#define LCELL 8                   // per-(split,class) sorted list depth
#define NSPLIT 2
#define NCAND (16 * LCELL * NSPLIT)  // 256 candidates per query into refine
#define CNT_TOTAL (B_ * N_ * K_)  // 655360
#define BN_EPSF 1e-5f

__device__ __forceinline__ f32x4 max4(f32x4 a, f32x4 b) {
  f32x4 r;
  r.x = fmaxf(a.x, b.x); r.y = fmaxf(a.y, b.y);
  r.z = fmaxf(a.z, b.z); r.w = fmaxf(a.w, b.w);
  return r;
}
__device__ __forceinline__ f32x4 min4(f32x4 a, f32x4 b) {
  f32x4 r;
  r.x = fminf(a.x, b.x); r.y = fminf(a.y, b.y);
  r.z = fminf(a.z, b.z); r.w = fminf(a.w, b.w);
  return r;
}

// ---- Kernel 1: transpose x -> xt (f32 + f16), per-point sq (f32+f64),
// y1 = xt*W1^T, y2 = xt*W2^T - y1. W row o==lane held in 128 VGPRs.
__global__ __launch_bounds__(256) void prep_kernel(
    const float* __restrict__ x, const float* __restrict__ W,
    float* __restrict__ xt, _Float16* __restrict__ xt16,
    float* __restrict__ sq, double* __restrict__ sqd,
    float* __restrict__ y1, float* __restrict__ y2) {
  __shared__ float xs[64 * 68];  // [n][c], stride 68 (16B-aligned rows)
  int b = blockIdx.x >> 7;
  int n0 = (blockIdx.x & 127) * 64;
  int t = threadIdx.x;
  int lane = t & 63;
  int wv = t >> 6;
#pragma unroll
  for (int i = 0; i < 16; ++i) {
    int lin = i * 256 + t;
    int c = lin >> 6, j = lin & 63;
    xs[j * 68 + c] = x[((b * 64 + c) * N_) + n0 + j];
  }
  // W row o = lane into registers (L1/L2-hot, 32 KB total)
  float4 w1[16], w2[16];
  const float4* wr = (const float4*)(W + lane * 128);
#pragma unroll
  for (int u = 0; u < 16; ++u) {
    w1[u] = wr[u];
    w2[u] = wr[16 + u];
  }
  __syncthreads();
#pragma unroll 2
  for (int i = 0; i < 16; ++i) {
    int nl = i * 4 + wv;
    const float4* xr = (const float4*)&xs[nl * 68];
    float d1 = 0.f, d2 = 0.f;
#pragma unroll
    for (int u = 0; u < 16; ++u) {
      float4 xv = xr[u];
      d1 = fmaf(xv.x, w1[u].x, d1); d1 = fmaf(xv.y, w1[u].y, d1);
      d1 = fmaf(xv.z, w1[u].z, d1); d1 = fmaf(xv.w, w1[u].w, d1);
      d2 = fmaf(xv.x, w2[u].x, d2); d2 = fmaf(xv.y, w2[u].y, d2);
      d2 = fmaf(xv.z, w2[u].z, d2); d2 = fmaf(xv.w, w2[u].w, d2);
    }
    int n = n0 + nl;
    y1[((b * N_) + n) * 64 + lane] = d1;
    y2[((b * N_) + n) * 64 + lane] = d2 - d1;
  }
#pragma unroll
  for (int i = 0; i < 16; ++i) {
    int lin = i * 256 + t;
    int c = lin & 63, nl = lin >> 6;
    float v = xs[nl * 68 + c];
    size_t o = ((size_t)(b * N_) + n0 + nl) * 64 + c;
    xt[o] = v;
    xt16[o] = (_Float16)v;
  }
  if (t < 64) {
    float s = 0.f;
    double sd = 0.0;
#pragma unroll
    for (int c = 0; c < 64; ++c) {
      float v = xs[t * 68 + c];
      s = fmaf(v, v, s);
      sd = fma((double)v, (double)v, sd);
    }
    sq[b * N_ + n0 + t] = s;
    sqd[b * N_ + n0 + t] = sd;
  }
}

// ---- Kernel 2: MFMA distance scan over one of 2 candidate splits (4096
// cands). Branchless clamp top-8 per (query,class). Packed key:
// (float_bits(sqc+512-2dot) & ~255) | tile_id(8b). Incremental pointers,
// 2x unrolled (no B-copy movs). __launch_bounds__(256,4): 128-VGPR budget
// so dl[] stays in arch VGPRs (no accvgpr round-trips).
__global__ __launch_bounds__(256, 4) void knn_mfma_kernel(
    const _Float16* __restrict__ xt16, const float* __restrict__ sq,
    int* __restrict__ pidx) {
  int t = threadIdx.x;
  int wave = t >> 6;
  int lane = t & 63;
  int col = lane & 15;
  int quad = lane >> 4;
  int blk = blockIdx.x;
  int split = blk & 1;
  int qt = (blk >> 1) & 127;
  int b = blk >> 8;
  int q0 = qt * 64 + wave * 16;
  size_t bbase = (size_t)b * N_;

  // A fragments: A[m=col][k=quad*8+j] -> query row q0+col
  const _Float16* arow = xt16 + (bbase + q0 + col) * 64;
  half8 A0 = *(const half8*)(arow + quad * 8);
  half8 A1 = *(const half8*)(arow + 32 + quad * 8);

  int dl[4][LCELL];
#pragma unroll
  for (int r = 0; r < 4; ++r)
#pragma unroll
    for (int j = 0; j < LCELL; ++j) dl[r][j] = 0x7fffffff;

  int c0 = split * (N_ / NSPLIT);
  const _Float16* bp = xt16 + (bbase + c0 + col) * 64 + quad * 8;
  const float* sp = sq + bbase + c0 + col;
  half8 B0 = *(const half8*)bp;
  half8 B1 = *(const half8*)(bp + 32);
  float sc = *sp;

  for (int ct = 0; ct < N_ / NSPLIT / 16; ct += 2) {
    // prefetch tile ct+1
    half8 C0 = *(const half8*)(bp + 1024);
    half8 C1 = *(const half8*)(bp + 1024 + 32);
    float sc1 = sp[16];

    f32x4 acc = {0.f, 0.f, 0.f, 0.f};
    acc = __builtin_amdgcn_mfma_f32_16x16x32_f16(A0, B0, acc, 0, 0, 0);
    acc = __builtin_amdgcn_mfma_f32_16x16x32_f16(A1, B1, acc, 0, 0, 0);
    float k512 = sc + 512.0f;
#pragma unroll
    for (int r = 0; r < 4; ++r) {
      float key = fmaf(acc[r], -2.0f, k512);  // positive by construction
      int v = (__float_as_int(key) & ~255) | ct;
#pragma unroll
      for (int j = LCELL - 1; j >= 1; --j)
        dl[r][j] = min(max(v, dl[r][j - 1]), dl[r][j]);
      dl[r][0] = min(dl[r][0], v);
    }

    // prefetch tile ct+2
    B0 = *(const half8*)(bp + 2048);
    B1 = *(const half8*)(bp + 2048 + 32);
    sc = sp[32];

    f32x4 acc2 = {0.f, 0.f, 0.f, 0.f};
    acc2 = __builtin_amdgcn_mfma_f32_16x16x32_f16(A0, C0, acc2, 0, 0, 0);
    acc2 = __builtin_amdgcn_mfma_f32_16x16x32_f16(A1, C1, acc2, 0, 0, 0);
    float k512b = sc1 + 512.0f;
    int ctb = ct + 1;
#pragma unroll
    for (int r = 0; r < 4; ++r) {
      float key = fmaf(acc2[r], -2.0f, k512b);
      int v = (__float_as_int(key) & ~255) | ctb;
#pragma unroll
      for (int j = LCELL - 1; j >= 1; --j)
        dl[r][j] = min(max(v, dl[r][j - 1]), dl[r][j]);
      dl[r][0] = min(dl[r][0], v);
    }
    bp += 2048;
    sp += 32;
  }
#pragma unroll
  for (int r = 0; r < 4; ++r) {
    int q = q0 + quad * 4 + r;
    int* o = pidx + (bbase + q) * NCAND + split * (16 * LCELL) + col * LCELL;
#pragma unroll
    for (int j = 0; j < LCELL; ++j)
      o[j] = ((dl[r][j] & 255) << 4) + col + c0;  // global candidate index
  }
}

// ---- Kernel 3: refinement v6 — one WAVE per point, two-phase, query in LDS.
// Phase 1: wave's query row staged once into LDS (1 KB/block); lane owns 4
// candidates, fp32 dot with ds_read_b128 broadcast of query chunks (live
// regs ~40 -> no spill at the compiler's 64-VGPR allocation). Key packed as
// (double)fp32key with 13-bit index in the 29 zero mantissa bits. Sort-4.
// Phase 2: 24 pop-min steps (6-shfl f64 butterfly); each popped candidate
// recomputed EXACTLY in cooperative fp64 (identical math to passing rounds).
// Final: 20 pop-min over the 24 exact keys. fp32 error ~1e-5 << gaps.
__global__ __launch_bounds__(256) void refine_kernel(
    const float* __restrict__ xt, const float* __restrict__ sq,
    const double* __restrict__ sqd, const int* __restrict__ pidx,
    int* __restrict__ idxf) {
  __shared__ float qs[4][64];
  int tid = threadIdx.x;
  int wave = tid >> 6, lane = tid & 63;
  int u = lane & 15;
  int p = blockIdx.x * 4 + wave;  // global point id
  int b = p >> 13;
  size_t bbase = (size_t)b * N_;
  int plocal = p & (N_ - 1);

  // stage query row into LDS (lanes 0..15 write 16B each)
  if (lane < 16) {
    ((f32x4*)qs[wave])[lane] = ((const f32x4*)(xt + (size_t)p * 64))[lane];
  }
  // phase 1: 4 whole candidates per lane, fp32 dots vs LDS-broadcast query
  const int* pi = pidx + (size_t)p * NCAND + lane * 4;
  int4 cc = *(const int4*)pi;
  int cs[4] = {cc.x, cc.y, cc.z, cc.w};
  double dl[4];
#pragma unroll
  for (int j = 0; j < 4; ++j) {
    int ci = cs[j];
    const f32x4* cr = (const f32x4*)(xt + (bbase + ci) * 64);
    const f32x4* qr = (const f32x4*)qs[wave];
    float a0 = 0.f, a1 = 0.f, a2 = 0.f, a3 = 0.f;
#pragma unroll
    for (int t2 = 0; t2 < 16; ++t2) {
      f32x4 v = cr[t2];
      f32x4 qv = qr[t2];  // ds_read_b128, wave-uniform -> broadcast
      a0 = fmaf(v.x, qv.x, a0);
      a1 = fmaf(v.y, qv.y, a1);
      a2 = fmaf(v.z, qv.z, a2);
      a3 = fmaf(v.w, qv.w, a3);
    }
    float dot = (a0 + a1) + (a2 + a3);
    float key = fmaf(dot, -2.0f, sq[bbase + ci]) + 512.0f;  // > 0
    long long bits =
        (__double_as_longlong((double)key) & ~0x1FFFLL) | (long long)ci;
    double v = __longlong_as_double(bits);
    if (ci == plocal) v = 1e300;  // self-exclusion
    dl[j] = v;
  }
  {  // sort 4 ascending
    double lo, hi;
    lo = fmin(dl[0], dl[1]); hi = fmax(dl[0], dl[1]); dl[0] = lo; dl[1] = hi;
    lo = fmin(dl[2], dl[3]); hi = fmax(dl[2], dl[3]); dl[2] = lo; dl[3] = hi;
    lo = fmin(dl[0], dl[2]); hi = fmax(dl[0], dl[2]); dl[0] = lo; dl[2] = hi;
    lo = fmin(dl[1], dl[3]); hi = fmax(dl[1], dl[3]); dl[1] = lo; dl[3] = hi;
    lo = fmin(dl[1], dl[2]); hi = fmax(dl[1], dl[2]); dl[1] = lo; dl[2] = hi;
  }
  double vh = dl[0], h1 = dl[1], h2 = dl[2], h3 = dl[3];

  // phase-2 query chunk in fp64 (dims u*4..u*4+3) from LDS
  f32x4 qc = ((const f32x4*)qs[wave])[u];
  double q0 = (double)qc.x, q1 = (double)qc.y;
  double q2 = (double)qc.z, q3 = (double)qc.w;

  double kv = 1e300;  // exact-key slot (lanes 0..23)
#pragma unroll
  for (int s = 0; s < 24; ++s) {
    double m = vh;
    m = fmin(m, __shfl_xor(m, 1, 64));
    m = fmin(m, __shfl_xor(m, 2, 64));
    m = fmin(m, __shfl_xor(m, 4, 64));
    m = fmin(m, __shfl_xor(m, 8, 64));
    m = fmin(m, __shfl_xor(m, 16, 64));
    m = fmin(m, __shfl_xor(m, 32, 64));
    int ci = (int)(__double_as_longlong(m) & 0x1FFFLL);
    // exact fp64 key (cooperative, identical math to passing rounds)
    f32x4 cv = *(const f32x4*)(xt + (bbase + ci) * 64 + u * 4);
    double a = q0 * (double)cv.x;
    a = fma(q1, (double)cv.y, a);
    a = fma(q2, (double)cv.z, a);
    a = fma(q3, (double)cv.w, a);
    a += __shfl_xor(a, 1, 64);
    a += __shfl_xor(a, 2, 64);
    a += __shfl_xor(a, 4, 64);
    a += __shfl_xor(a, 8, 64);
    double kd = fma(a, -2.0, sqd[bbase + ci]) + 1024.0;
    long long kb = (__double_as_longlong(kd) & ~0x1FFFLL) | (long long)ci;
    double vv = __longlong_as_double(kb);
    kv = (lane == s) ? vv : kv;
    bool adv = (vh == m);  // unique keys: exactly one owner advances
    vh = adv ? h1 : vh;
    h1 = adv ? h2 : h1;
    h2 = adv ? h3 : h2;
    h3 = adv ? 1e300 : h3;
  }
  // final: 20 smallest of the 24 exact keys (ascending, index tie-break)
  int* o = idxf + (size_t)p * K_;
#pragma unroll
  for (int s = 0; s < K_; ++s) {
    double m = kv;
    m = fmin(m, __shfl_xor(m, 1, 64));
    m = fmin(m, __shfl_xor(m, 2, 64));
    m = fmin(m, __shfl_xor(m, 4, 64));
    m = fmin(m, __shfl_xor(m, 8, 64));
    m = fmin(m, __shfl_xor(m, 16, 64));
    m = fmin(m, __shfl_xor(m, 32, 64));
    if (lane == 0) o[s] = (int)(__double_as_longlong(m) & 0x1FFFLL);
    kv = (kv == m) ? 1e300 : kv;
  }
}

// ---- Kernel 4: one WAVE per point. Lane (u=lane&15, jb=lane>>4); 5 rounds:
// lane loads 16B chunk u of neighbor jb+4r -> each 16-lane group reads a full
// 256B y1 row per instruction (no partial lines). max/min/sum/sumsq of the
// gathered y1 reduced across jb via shfl_xor(16,32); y2 applied once:
// max(h)=max(g)+y2, sum(h)=sum(g)+K*y2, sumsq(h)=sum(g^2)+2*y2*sum(g)+K*y2^2.
// 4 points per wave sequentially; BN sums -> LDS atomics -> 128 global/block.
__global__ __launch_bounds__(256) void stats_kernel(
    const float* __restrict__ y1, const float* __restrict__ y2,
    const int* __restrict__ idxf, float* __restrict__ maxh,
    float* __restrict__ minh, float* __restrict__ gsum,
    float* __restrict__ gsq) {
  __shared__ float lsum[64], lsq[64];
  int tid = threadIdx.x;
  if (tid < 64) { lsum[tid] = 0.f; lsq[tid] = 0.f; }
  __syncthreads();
  int wv = tid >> 6, lane = tid & 63;
  int u = lane & 15, jb = lane >> 4;
  int p0 = blockIdx.x * 16 + wv * 4;  // 16 contiguous points per block
  size_t nb = (size_t)((p0 >> 13) * N_);
  f32x4 css = {0.f, 0.f, 0.f, 0.f}, cqq = {0.f, 0.f, 0.f, 0.f};
#pragma unroll
  for (int it = 0; it < 4; ++it) {
    int p = p0 + it;
    int idxval = (lane < K_) ? idxf[(size_t)p * K_ + lane] : 0;
    int n0 = __shfl(idxval, jb, 64);
    int n1 = __shfl(idxval, jb + 4, 64);
    int n2 = __shfl(idxval, jb + 8, 64);
    int n3 = __shfl(idxval, jb + 12, 64);
    int n4 = __shfl(idxval, jb + 16, 64);
    f32x4 g0 = ((const f32x4*)(y1 + (nb + n0) * 64))[u];
    f32x4 g1 = ((const f32x4*)(y1 + (nb + n1) * 64))[u];
    f32x4 g2 = ((const f32x4*)(y1 + (nb + n2) * 64))[u];
    f32x4 g3 = ((const f32x4*)(y1 + (nb + n3) * 64))[u];
    f32x4 g4 = ((const f32x4*)(y1 + (nb + n4) * 64))[u];
    f32x4 mx = g0, mn = g0, sm = g0, s2 = g0 * g0;
    mx = max4(mx, g1); mn = min4(mn, g1); sm += g1; s2 += g1 * g1;
    mx = max4(mx, g2); mn = min4(mn, g2); sm += g2; s2 += g2 * g2;
    mx = max4(mx, g3); mn = min4(mn, g3); sm += g3; s2 += g3 * g3;
    mx = max4(mx, g4); mn = min4(mn, g4); sm += g4; s2 += g4 * g4;
#pragma unroll
    for (int c = 0; c < 4; ++c) {
      mx[c] = fmaxf(mx[c], __shfl_xor(mx[c], 16, 64));
      mx[c] = fmaxf(mx[c], __shfl_xor(mx[c], 32, 64));
      mn[c] = fminf(mn[c], __shfl_xor(mn[c], 16, 64));
      mn[c] = fminf(mn[c], __shfl_xor(mn[c], 32, 64));
      sm[c] += __shfl_xor(sm[c], 16, 64);
      sm[c] += __shfl_xor(sm[c], 32, 64);
      s2[c] += __shfl_xor(s2[c], 16, 64);
      s2[c] += __shfl_xor(s2[c], 32, 64);
    }
    if (jb == 0) {  // lanes 0..15: full 256B contiguous stores
      f32x4 y2c = ((const f32x4*)(y2 + (size_t)p * 64))[u];
      ((f32x4*)(maxh + (size_t)p * 64))[u] = mx + y2c;
      ((f32x4*)(minh + (size_t)p * 64))[u] = mn + y2c;
      css += sm + 20.0f * y2c;
      cqq += s2 + 2.0f * y2c * sm + 20.0f * y2c * y2c;
    }
  }
  if (jb == 0) {
#pragma unroll
    for (int c = 0; c < 4; ++c) {
      atomicAdd(&lsum[u * 4 + c], css[c]);
      atomicAdd(&lsq[u * 4 + c], cqq[c]);
    }
  }
  __syncthreads();
  if (tid < 64) {
    atomicAdd(&gsum[tid], lsum[tid]);
    atomicAdd(&gsq[tid], lsq[tid]);
  }
}

// ---- Kernel 5: affine + relu + max-over-k selection, transposed store ----
__global__ __launch_bounds__(256) void final_kernel(
    const float* __restrict__ maxh, const float* __restrict__ minh,
    const float* __restrict__ gsum, const float* __restrict__ gsq,
    const float* __restrict__ gamma, const float* __restrict__ beta,
    float* __restrict__ out) {
  __shared__ float sc[64], cc_[64];
  __shared__ float tile[64 * 65];
  int b = blockIdx.x >> 7;
  int n0 = (blockIdx.x & 127) * 64;
  int t = threadIdx.x;
  if (t < 64) {
    float mean = gsum[t] * (1.0f / CNT_TOTAL);
    float var = gsq[t] * (1.0f / CNT_TOTAL) - mean * mean;
    float s = gamma[t] * rsqrtf(var + BN_EPSF);
    sc[t] = s;
    cc_[t] = beta[t] - mean * s;
  }
  __syncthreads();
#pragma unroll
  for (int i = 0; i < 16; ++i) {
    int lin = i * 256 + t;
    int o = lin & 63, nl = lin >> 6;
    size_t off = ((size_t)(b * N_) + n0 + nl) * 64 + o;
    float s = sc[o];
    float v = (s >= 0.f) ? maxh[off] : minh[off];
    float val = fmaxf(fmaf(v, s, cc_[o]), 0.f);
    tile[o * 65 + nl] = val;
  }
  __syncthreads();
#pragma unroll
  for (int i = 0; i < 16; ++i) {
    int lin = i * 256 + t;
    int nl = lin & 63, o = lin >> 6;
    out[((size_t)(b * 64) + o) * N_ + n0 + nl] = tile[o * 65 + nl];
  }
}

extern "C" void kernel_launch(void* const* d_in, const int* in_sizes, int n_in,
                              void* d_out, int out_size, void* d_ws,
                              size_t ws_size, hipStream_t stream) {
  const float* x = (const float*)d_in[0];
  const float* W = (const float*)d_in[1];
  const float* gamma = (const float*)d_in[2];
  const float* beta = (const float*)d_in[3];
  float* out = (float*)d_out;

  char* ws = (char*)d_ws;
  size_t off = 0;
  auto alloc = [&](size_t bytes) {
    char* p = ws + off;
    off += (bytes + 255) & ~(size_t)255;
    return p;
  };
  float* xt = (float*)alloc((size_t)B_ * N_ * 64 * 4);
  _Float16* xt16 = (_Float16*)alloc((size_t)B_ * N_ * 64 * 2);
  float* y1 = (float*)alloc((size_t)B_ * N_ * 64 * 4);
  float* y2 = (float*)alloc((size_t)B_ * N_ * 64 * 4);
  float* sq = (float*)alloc((size_t)B_ * N_ * 4);
  double* sqd = (double*)alloc((size_t)B_ * N_ * 8);
  int* pidx = (int*)alloc((size_t)B_ * N_ * NCAND * 4);  // 33.5 MB
  float* maxh = (float*)alloc((size_t)B_ * N_ * 64 * 4);
  int* idxf = (int*)alloc((size_t)B_ * N_ * K_ * 4);
  float* gsum = (float*)alloc(256);
  float* gsq = (float*)alloc(256);
  // minh aliases pidx (pidx fully consumed by refine before stats runs)
  float* minh = (float*)pidx;

  hipMemsetAsync(gsum, 0, 256, stream);
  hipMemsetAsync(gsq, 0, 256, stream);

  prep_kernel<<<B_ * (N_ / 64), 256, 0, stream>>>(x, W, xt, xt16, sq, sqd,
                                                  y1, y2);
  knn_mfma_kernel<<<B_ * (N_ / 64) * NSPLIT, 256, 0, stream>>>(xt16, sq, pidx);
  refine_kernel<<<(B_ * N_) / 4, 256, 0, stream>>>(xt, sq, sqd, pidx, idxf);
  stats_kernel<<<(B_ * N_) / 16, 256, 0, stream>>>(y1, y2, idxf, maxh, minh,
                                                   gsum, gsq);
  final_kernel<<<B_ * (N_ / 64), 256, 0, stream>>>(maxh, minh, gsum, gsq,
                                                   gamma, beta, out);
}

// Round 13
// 618.776 us; speedup vs baseline: 1.4913x; 1.1877x over previous
//
#include <hip/hip_runtime.h>

typedef _Float16 half8 __attribute__((ext_vector_type(8)));
typedef float f32x4 __attribute__((ext_vector_type(4)));

#define B_ 4
#define C_ 64
#define N_ 8192
#define K_ 20
#define LCELL 8                   // per-(split,class) sorted list depth
#define NSPLIT 2
#define NCAND (16 * LCELL * NSPLIT)  // 256 candidates per query into refine
#define CNT_TOTAL (B_ * N_ * K_)  // 655360
#define BN_EPSF 1e-5f

__device__ __forceinline__ f32x4 max4(f32x4 a, f32x4 b) {
  f32x4 r;
  r.x = fmaxf(a.x, b.x); r.y = fmaxf(a.y, b.y);
  r.z = fmaxf(a.z, b.z); r.w = fmaxf(a.w, b.w);
  return r;
}
__device__ __forceinline__ f32x4 min4(f32x4 a, f32x4 b) {
  f32x4 r;
  r.x = fminf(a.x, b.x); r.y = fminf(a.y, b.y);
  r.z = fminf(a.z, b.z); r.w = fminf(a.w, b.w);
  return r;
}

// ---- Kernel 1: transpose x -> xt (f32 + f16), per-point sq (f32+f64),
// y1 = xt*W1^T, y2 = xt*W2^T - y1. W row o==lane held in 128 VGPRs.
__global__ __launch_bounds__(256) void prep_kernel(
    const float* __restrict__ x, const float* __restrict__ W,
    float* __restrict__ xt, _Float16* __restrict__ xt16,
    float* __restrict__ sq, double* __restrict__ sqd,
    float* __restrict__ y1, float* __restrict__ y2) {
  __shared__ float xs[64 * 68];  // [n][c], stride 68 (16B-aligned rows)
  int b = blockIdx.x >> 7;
  int n0 = (blockIdx.x & 127) * 64;
  int t = threadIdx.x;
  int lane = t & 63;
  int wv = t >> 6;
#pragma unroll
  for (int i = 0; i < 16; ++i) {
    int lin = i * 256 + t;
    int c = lin >> 6, j = lin & 63;
    xs[j * 68 + c] = x[((b * 64 + c) * N_) + n0 + j];
  }
  // W row o = lane into registers (L1/L2-hot, 32 KB total)
  float4 w1[16], w2[16];
  const float4* wr = (const float4*)(W + lane * 128);
#pragma unroll
  for (int u = 0; u < 16; ++u) {
    w1[u] = wr[u];
    w2[u] = wr[16 + u];
  }
  __syncthreads();
#pragma unroll 2
  for (int i = 0; i < 16; ++i) {
    int nl = i * 4 + wv;
    const float4* xr = (const float4*)&xs[nl * 68];
    float d1 = 0.f, d2 = 0.f;
#pragma unroll
    for (int u = 0; u < 16; ++u) {
      float4 xv = xr[u];
      d1 = fmaf(xv.x, w1[u].x, d1); d1 = fmaf(xv.y, w1[u].y, d1);
      d1 = fmaf(xv.z, w1[u].z, d1); d1 = fmaf(xv.w, w1[u].w, d1);
      d2 = fmaf(xv.x, w2[u].x, d2); d2 = fmaf(xv.y, w2[u].y, d2);
      d2 = fmaf(xv.z, w2[u].z, d2); d2 = fmaf(xv.w, w2[u].w, d2);
    }
    int n = n0 + nl;
    y1[((b * N_) + n) * 64 + lane] = d1;
    y2[((b * N_) + n) * 64 + lane] = d2 - d1;
  }
#pragma unroll
  for (int i = 0; i < 16; ++i) {
    int lin = i * 256 + t;
    int c = lin & 63, nl = lin >> 6;
    float v = xs[nl * 68 + c];
    size_t o = ((size_t)(b * N_) + n0 + nl) * 64 + c;
    xt[o] = v;
    xt16[o] = (_Float16)v;
  }
  if (t < 64) {
    float s = 0.f;
    double sd = 0.0;
#pragma unroll
    for (int c = 0; c < 64; ++c) {
      float v = xs[t * 68 + c];
      s = fmaf(v, v, s);
      sd = fma((double)v, (double)v, sd);
    }
    sq[b * N_ + n0 + t] = s;
    sqd[b * N_ + n0 + t] = sd;
  }
}

// ---- Kernel 2: MFMA distance scan over one of 2 candidate splits (4096
// cands). Branchless clamp top-8 per (query,class). Packed value:
// (float_bits(sqc+512-2dot) & ~255) | tile_id(8b) — stored RAW; refine
// reconstructs (key, global index) from (value, slot). Incremental
// pointers, 2x unrolled. __launch_bounds__(256,4): dl[] stays in VGPRs.
__global__ __launch_bounds__(256, 4) void knn_mfma_kernel(
    const _Float16* __restrict__ xt16, const float* __restrict__ sq,
    int* __restrict__ pidx) {
  int t = threadIdx.x;
  int wave = t >> 6;
  int lane = t & 63;
  int col = lane & 15;
  int quad = lane >> 4;
  int blk = blockIdx.x;
  int split = blk & 1;
  int qt = (blk >> 1) & 127;
  int b = blk >> 8;
  int q0 = qt * 64 + wave * 16;
  size_t bbase = (size_t)b * N_;

  // A fragments: A[m=col][k=quad*8+j] -> query row q0+col
  const _Float16* arow = xt16 + (bbase + q0 + col) * 64;
  half8 A0 = *(const half8*)(arow + quad * 8);
  half8 A1 = *(const half8*)(arow + 32 + quad * 8);

  int dl[4][LCELL];
#pragma unroll
  for (int r = 0; r < 4; ++r)
#pragma unroll
    for (int j = 0; j < LCELL; ++j) dl[r][j] = 0x7fffffff;

  int c0 = split * (N_ / NSPLIT);
  const _Float16* bp = xt16 + (bbase + c0 + col) * 64 + quad * 8;
  const float* sp = sq + bbase + c0 + col;
  half8 B0 = *(const half8*)bp;
  half8 B1 = *(const half8*)(bp + 32);
  float sc = *sp;

  for (int ct = 0; ct < N_ / NSPLIT / 16; ct += 2) {
    // prefetch tile ct+1
    half8 C0 = *(const half8*)(bp + 1024);
    half8 C1 = *(const half8*)(bp + 1024 + 32);
    float sc1 = sp[16];

    f32x4 acc = {0.f, 0.f, 0.f, 0.f};
    acc = __builtin_amdgcn_mfma_f32_16x16x32_f16(A0, B0, acc, 0, 0, 0);
    acc = __builtin_amdgcn_mfma_f32_16x16x32_f16(A1, B1, acc, 0, 0, 0);
    float k512 = sc + 512.0f;
#pragma unroll
    for (int r = 0; r < 4; ++r) {
      float key = fmaf(acc[r], -2.0f, k512);  // positive by construction
      int v = (__float_as_int(key) & ~255) | ct;
#pragma unroll
      for (int j = LCELL - 1; j >= 1; --j)
        dl[r][j] = min(max(v, dl[r][j - 1]), dl[r][j]);
      dl[r][0] = min(dl[r][0], v);
    }

    // prefetch tile ct+2
    B0 = *(const half8*)(bp + 2048);
    B1 = *(const half8*)(bp + 2048 + 32);
    sc = sp[32];

    f32x4 acc2 = {0.f, 0.f, 0.f, 0.f};
    acc2 = __builtin_amdgcn_mfma_f32_16x16x32_f16(A0, C0, acc2, 0, 0, 0);
    acc2 = __builtin_amdgcn_mfma_f32_16x16x32_f16(A1, C1, acc2, 0, 0, 0);
    float k512b = sc1 + 512.0f;
    int ctb = ct + 1;
#pragma unroll
    for (int r = 0; r < 4; ++r) {
      float key = fmaf(acc2[r], -2.0f, k512b);
      int v = (__float_as_int(key) & ~255) | ctb;
#pragma unroll
      for (int j = LCELL - 1; j >= 1; --j)
        dl[r][j] = min(max(v, dl[r][j - 1]), dl[r][j]);
      dl[r][0] = min(dl[r][0], v);
    }
    bp += 2048;
    sp += 32;
  }
#pragma unroll
  for (int r = 0; r < 4; ++r) {
    int q = q0 + quad * 4 + r;
    int* o = pidx + (bbase + q) * NCAND + split * (16 * LCELL) + col * LCELL;
#pragma unroll
    for (int j = 0; j < LCELL; ++j) o[j] = dl[r][j];  // raw packed value
  }
}

// ---- Kernel 3: refinement v7 — one WAVE per point, key-reuse.
// Stage 1: lane loads its 4 raw packed scan values (int4); reconstructs
// (approx key, global index) from (value, slot): col=(slot>>3)&15,
// split=slot>>7, ci=((v&255)<<4)+col+split*4096. Packs unique doubles
// ((double)key with 13-bit index in zero mantissa bits), sort-4.
// Stage 2: 32 approx pop-min steps (6-shfl f64 butterfly, no memory);
// popped candidate s -> lane s. Margin: key error <= ~0.1 (f16 MFMA +
// 8-bit mask) << rank-20..32 distance span -> true top-20 in approx-top-32.
// Stage 3: lanes 0..31 IN PARALLEL compute their candidate's full fp64
// dot vs LDS-broadcast query row (64 f64 FMA, 4 accums); exact key =
// sqd - 2*dot + 1024, index in mantissa (math identical to passing rounds).
// Stage 4: 20 pop-min over exact keys emit indices (fp64 rank + idx tie).
__global__ __launch_bounds__(256) void refine_kernel(
    const float* __restrict__ xt, const double* __restrict__ sqd,
    const int* __restrict__ pidx, int* __restrict__ idxf) {
  __shared__ float qs[4][64];
  int tid = threadIdx.x;
  int wave = tid >> 6, lane = tid & 63;
  int p = blockIdx.x * 4 + wave;  // global point id
  int b = p >> 13;
  size_t bbase = (size_t)b * N_;
  int plocal = p & (N_ - 1);

  // stage query row into LDS (lanes 0..15 write 16B each)
  if (lane < 16) {
    ((f32x4*)qs[wave])[lane] = ((const f32x4*)(xt + (size_t)p * 64))[lane];
  }
  // stage 1: 4 packed values per lane -> unique double keys
  const int* pi = pidx + (size_t)p * NCAND + lane * 4;
  int4 cc = *(const int4*)pi;
  int vs[4] = {cc.x, cc.y, cc.z, cc.w};
  double dl[4];
#pragma unroll
  for (int j = 0; j < 4; ++j) {
    int slot = lane * 4 + j;
    int col = (slot >> 3) & 15;
    int split = slot >> 7;
    int dlv = vs[j];
    int ci = ((dlv & 255) << 4) + col + split * (N_ / NSPLIT);
    float key = __int_as_float(dlv & ~255);  // positive
    long long bits =
        (__double_as_longlong((double)key) & ~0x1FFFLL) | (long long)ci;
    double v = __longlong_as_double(bits);
    if (ci == plocal) v = 1e300;  // self-exclusion
    dl[j] = v;
  }
  {  // sort 4 ascending
    double lo, hi;
    lo = fmin(dl[0], dl[1]); hi = fmax(dl[0], dl[1]); dl[0] = lo; dl[1] = hi;
    lo = fmin(dl[2], dl[3]); hi = fmax(dl[2], dl[3]); dl[2] = lo; dl[3] = hi;
    lo = fmin(dl[0], dl[2]); hi = fmax(dl[0], dl[2]); dl[0] = lo; dl[2] = hi;
    lo = fmin(dl[1], dl[3]); hi = fmax(dl[1], dl[3]); dl[1] = lo; dl[3] = hi;
    lo = fmin(dl[1], dl[2]); hi = fmax(dl[1], dl[2]); dl[1] = lo; dl[2] = hi;
  }
  double vh = dl[0], h1 = dl[1], h2 = dl[2], h3 = dl[3];

  // stage 2: 32 approx pops; popped candidate s -> lane s
  int myci = 0;
#pragma unroll
  for (int s = 0; s < 32; ++s) {
    double m = vh;
    m = fmin(m, __shfl_xor(m, 1, 64));
    m = fmin(m, __shfl_xor(m, 2, 64));
    m = fmin(m, __shfl_xor(m, 4, 64));
    m = fmin(m, __shfl_xor(m, 8, 64));
    m = fmin(m, __shfl_xor(m, 16, 64));
    m = fmin(m, __shfl_xor(m, 32, 64));
    if (lane == s) myci = (int)(__double_as_longlong(m) & 0x1FFFLL);
    bool adv = (vh == m);  // unique keys: exactly one owner advances
    vh = adv ? h1 : vh;
    h1 = adv ? h2 : h1;
    h2 = adv ? h3 : h2;
    h3 = adv ? 1e300 : h3;
  }
  // stage 3: parallel exact fp64 keys on lanes 0..31
  double kv = 1e300;
  if (lane < 32) {
    const f32x4* cr = (const f32x4*)(xt + (bbase + myci) * 64);
    const f32x4* qr = (const f32x4*)qs[wave];
    double a0 = 0.0, a1 = 0.0, a2 = 0.0, a3 = 0.0;
#pragma unroll
    for (int t2 = 0; t2 < 16; ++t2) {
      f32x4 cv = cr[t2];
      f32x4 qv = qr[t2];  // ds_read_b128 broadcast
      a0 = fma((double)cv.x, (double)qv.x, a0);
      a1 = fma((double)cv.y, (double)qv.y, a1);
      a2 = fma((double)cv.z, (double)qv.z, a2);
      a3 = fma((double)cv.w, (double)qv.w, a3);
    }
    double dot = (a0 + a1) + (a2 + a3);
    double kd = fma(dot, -2.0, sqd[bbase + myci]) + 1024.0;
    kv = __longlong_as_double(
        (__double_as_longlong(kd) & ~0x1FFFLL) | (long long)myci);
  }
  // stage 4: 20 smallest exact keys (ascending, index tie-break)
  int* o = idxf + (size_t)p * K_;
#pragma unroll
  for (int s = 0; s < K_; ++s) {
    double m = kv;
    m = fmin(m, __shfl_xor(m, 1, 64));
    m = fmin(m, __shfl_xor(m, 2, 64));
    m = fmin(m, __shfl_xor(m, 4, 64));
    m = fmin(m, __shfl_xor(m, 8, 64));
    m = fmin(m, __shfl_xor(m, 16, 64));
    m = fmin(m, __shfl_xor(m, 32, 64));
    if (lane == 0) o[s] = (int)(__double_as_longlong(m) & 0x1FFFLL);
    kv = (kv == m) ? 1e300 : kv;
  }
}

// ---- Kernel 4: one WAVE per point. Lane (u=lane&15, jb=lane>>4); 5 rounds:
// lane loads 16B chunk u of neighbor jb+4r -> each 16-lane group reads a full
// 256B y1 row per instruction (no partial lines). max/min/sum/sumsq of the
// gathered y1 reduced across jb via shfl_xor(16,32); y2 applied once:
// max(h)=max(g)+y2, sum(h)=sum(g)+K*y2, sumsq(h)=sum(g^2)+2*y2*sum(g)+K*y2^2.
// 4 points per wave sequentially; BN sums -> LDS atomics -> 128 global/block.
__global__ __launch_bounds__(256) void stats_kernel(
    const float* __restrict__ y1, const float* __restrict__ y2,
    const int* __restrict__ idxf, float* __restrict__ maxh,
    float* __restrict__ minh, float* __restrict__ gsum,
    float* __restrict__ gsq) {
  __shared__ float lsum[64], lsq[64];
  int tid = threadIdx.x;
  if (tid < 64) { lsum[tid] = 0.f; lsq[tid] = 0.f; }
  __syncthreads();
  int wv = tid >> 6, lane = tid & 63;
  int u = lane & 15, jb = lane >> 4;
  int p0 = blockIdx.x * 16 + wv * 4;  // 16 contiguous points per block
  size_t nb = (size_t)((p0 >> 13) * N_);
  f32x4 css = {0.f, 0.f, 0.f, 0.f}, cqq = {0.f, 0.f, 0.f, 0.f};
#pragma unroll
  for (int it = 0; it < 4; ++it) {
    int p = p0 + it;
    int idxval = (lane < K_) ? idxf[(size_t)p * K_ + lane] : 0;
    int n0 = __shfl(idxval, jb, 64);
    int n1 = __shfl(idxval, jb + 4, 64);
    int n2 = __shfl(idxval, jb + 8, 64);
    int n3 = __shfl(idxval, jb + 12, 64);
    int n4 = __shfl(idxval, jb + 16, 64);
    f32x4 g0 = ((const f32x4*)(y1 + (nb + n0) * 64))[u];
    f32x4 g1 = ((const f32x4*)(y1 + (nb + n1) * 64))[u];
    f32x4 g2 = ((const f32x4*)(y1 + (nb + n2) * 64))[u];
    f32x4 g3 = ((const f32x4*)(y1 + (nb + n3) * 64))[u];
    f32x4 g4 = ((const f32x4*)(y1 + (nb + n4) * 64))[u];
    f32x4 mx = g0, mn = g0, sm = g0, s2 = g0 * g0;
    mx = max4(mx, g1); mn = min4(mn, g1); sm += g1; s2 += g1 * g1;
    mx = max4(mx, g2); mn = min4(mn, g2); sm += g2; s2 += g2 * g2;
    mx = max4(mx, g3); mn = min4(mn, g3); sm += g3; s2 += g3 * g3;
    mx = max4(mx, g4); mn = min4(mn, g4); sm += g4; s2 += g4 * g4;
#pragma unroll
    for (int c = 0; c < 4; ++c) {
      mx[c] = fmaxf(mx[c], __shfl_xor(mx[c], 16, 64));
      mx[c] = fmaxf(mx[c], __shfl_xor(mx[c], 32, 64));
      mn[c] = fminf(mn[c], __shfl_xor(mn[c], 16, 64));
      mn[c] = fminf(mn[c], __shfl_xor(mn[c], 32, 64));
      sm[c] += __shfl_xor(sm[c], 16, 64);
      sm[c] += __shfl_xor(sm[c], 32, 64);
      s2[c] += __shfl_xor(s2[c], 16, 64);
      s2[c] += __shfl_xor(s2[c], 32, 64);
    }
    if (jb == 0) {  // lanes 0..15: full 256B contiguous stores
      f32x4 y2c = ((const f32x4*)(y2 + (size_t)p * 64))[u];
      ((f32x4*)(maxh + (size_t)p * 64))[u] = mx + y2c;
      ((f32x4*)(minh + (size_t)p * 64))[u] = mn + y2c;
      css += sm + 20.0f * y2c;
      cqq += s2 + 2.0f * y2c * sm + 20.0f * y2c * y2c;
    }
  }
  if (jb == 0) {
#pragma unroll
    for (int c = 0; c < 4; ++c) {
      atomicAdd(&lsum[u * 4 + c], css[c]);
      atomicAdd(&lsq[u * 4 + c], cqq[c]);
    }
  }
  __syncthreads();
  if (tid < 64) {
    atomicAdd(&gsum[tid], lsum[tid]);
    atomicAdd(&gsq[tid], lsq[tid]);
  }
}

// ---- Kernel 5: affine + relu + max-over-k selection, transposed store ----
__global__ __launch_bounds__(256) void final_kernel(
    const float* __restrict__ maxh, const float* __restrict__ minh,
    const float* __restrict__ gsum, const float* __restrict__ gsq,
    const float* __restrict__ gamma, const float* __restrict__ beta,
    float* __restrict__ out) {
  __shared__ float sc[64], cc_[64];
  __shared__ float tile[64 * 65];
  int b = blockIdx.x >> 7;
  int n0 = (blockIdx.x & 127) * 64;
  int t = threadIdx.x;
  if (t < 64) {
    float mean = gsum[t] * (1.0f / CNT_TOTAL);
    float var = gsq[t] * (1.0f / CNT_TOTAL) - mean * mean;
    float s = gamma[t] * rsqrtf(var + BN_EPSF);
    sc[t] = s;
    cc_[t] = beta[t] - mean * s;
  }
  __syncthreads();
#pragma unroll
  for (int i = 0; i < 16; ++i) {
    int lin = i * 256 + t;
    int o = lin & 63, nl = lin >> 6;
    size_t off = ((size_t)(b * N_) + n0 + nl) * 64 + o;
    float s = sc[o];
    float v = (s >= 0.f) ? maxh[off] : minh[off];
    float val = fmaxf(fmaf(v, s, cc_[o]), 0.f);
    tile[o * 65 + nl] = val;
  }
  __syncthreads();
#pragma unroll
  for (int i = 0; i < 16; ++i) {
    int lin = i * 256 + t;
    int nl = lin & 63, o = lin >> 6;
    out[((size_t)(b * 64) + o) * N_ + n0 + nl] = tile[o * 65 + nl];
  }
}

extern "C" void kernel_launch(void* const* d_in, const int* in_sizes, int n_in,
                              void* d_out, int out_size, void* d_ws,
                              size_t ws_size, hipStream_t stream) {
  const float* x = (const float*)d_in[0];
  const float* W = (const float*)d_in[1];
  const float* gamma = (const float*)d_in[2];
  const float* beta = (const float*)d_in[3];
  float* out = (float*)d_out;

  char* ws = (char*)d_ws;
  size_t off = 0;
  auto alloc = [&](size_t bytes) {
    char* p = ws + off;
    off += (bytes + 255) & ~(size_t)255;
    return p;
  };
  float* xt = (float*)alloc((size_t)B_ * N_ * 64 * 4);
  _Float16* xt16 = (_Float16*)alloc((size_t)B_ * N_ * 64 * 2);
  float* y1 = (float*)alloc((size_t)B_ * N_ * 64 * 4);
  float* y2 = (float*)alloc((size_t)B_ * N_ * 64 * 4);
  float* sq = (float*)alloc((size_t)B_ * N_ * 4);
  double* sqd = (double*)alloc((size_t)B_ * N_ * 8);
  int* pidx = (int*)alloc((size_t)B_ * N_ * NCAND * 4);  // 33.5 MB
  float* maxh = (float*)alloc((size_t)B_ * N_ * 64 * 4);
  int* idxf = (int*)alloc((size_t)B_ * N_ * K_ * 4);
  float* gsum = (float*)alloc(256);
  float* gsq = (float*)alloc(256);
  // minh aliases pidx (pidx fully consumed by refine before stats runs)
  float* minh = (float*)pidx;

  hipMemsetAsync(gsum, 0, 256, stream);
  hipMemsetAsync(gsq, 0, 256, stream);

  prep_kernel<<<B_ * (N_ / 64), 256, 0, stream>>>(x, W, xt, xt16, sq, sqd,
                                                  y1, y2);
  knn_mfma_kernel<<<B_ * (N_ / 64) * NSPLIT, 256, 0, stream>>>(xt16, sq, pidx);
  refine_kernel<<<(B_ * N_) / 4, 256, 0, stream>>>(xt, sqd, pidx, idxf);
  stats_kernel<<<(B_ * N_) / 16, 256, 0, stream>>>(y1, y2, idxf, maxh, minh,
                                                   gsum, gsq);
  final_kernel<<<B_ * (N_ / 64), 256, 0, stream>>>(maxh, minh, gsum, gsq,
                                                   gamma, beta, out);
}